// Round 4
// baseline (397.837 us; speedup 1.0000x reference)
//
#include <hip/hip_runtime.h>

// GAT layer: B=2, N=50000, D=64, H=4, d=16, O=64, E=800000
#define N_NODES 50000
#define N_EDGES 800000
#define N_ROWS 100000           // B*N
#define NEG_SLOPE 0.1f
#define FC_S 68                 // LDS row stride (floats): 16B-aligned, 2-way-free

static __device__ __forceinline__ float lrelu(float z) {
    return (z > 0.f) ? z : NEG_SLOPE * z;
}

// ---- Kernel 1: feat = x @ W_fc.T (+ fused el/er) ----------------------------
// grid 1563: 64 rows x 64 cols per block; thread (tx=t&15, ty=t>>4) computes a
// 4x4 register tile at rows ty+{0,16,32,48}, cols tx+{0,16,32,48}.
__global__ __launch_bounds__(256) void k_fc(const float* __restrict__ x,
                                            const float* __restrict__ Wfc,
                                            const float* __restrict__ al,
                                            const float* __restrict__ ar,
                                            float* __restrict__ feat,
                                            float* __restrict__ el,
                                            float* __restrict__ er) {
    __shared__ float Ws[64 * FC_S];
    __shared__ float xs[64 * FC_S];
    const int t = threadIdx.x;
    const int tx = t & 15, ty = t >> 4;
    const int row0 = blockIdx.x * 64;
#pragma unroll
    for (int i = 0; i < 16; ++i) {          // stage W_fc [j][k]
        int p = i * 256 + t;
        Ws[(p >> 6) * FC_S + (p & 63)] = Wfc[p];
    }
#pragma unroll
    for (int i = 0; i < 16; ++i) {          // stage x rows (guard tail block)
        int p = i * 256 + t;
        int r = p >> 6, k = p & 63;
        int m = row0 + r;
        xs[r * FC_S + k] = (m < N_ROWS) ? x[m * 64 + k] : 0.f;
    }
    __syncthreads();

    float acc[4][4] = {};
#pragma unroll
    for (int k4 = 0; k4 < 16; ++k4) {
        float4 xv[4], wv[4];
#pragma unroll
        for (int i = 0; i < 4; ++i) {
            xv[i] = *(const float4*)&xs[(ty + i * 16) * FC_S + k4 * 4];
            wv[i] = *(const float4*)&Ws[(tx + i * 16) * FC_S + k4 * 4];
        }
#pragma unroll
        for (int ii = 0; ii < 4; ++ii)
#pragma unroll
            for (int jj = 0; jj < 4; ++jj) {
                acc[ii][jj] = fmaf(xv[ii].x, wv[jj].x, acc[ii][jj]);
                acc[ii][jj] = fmaf(xv[ii].y, wv[jj].y, acc[ii][jj]);
                acc[ii][jj] = fmaf(xv[ii].z, wv[jj].z, acc[ii][jj]);
                acc[ii][jj] = fmaf(xv[ii].w, wv[jj].w, acc[ii][jj]);
            }
    }

    // store feat
#pragma unroll
    for (int ii = 0; ii < 4; ++ii) {
        const int m = row0 + ty + ii * 16;
        if (m < N_ROWS) {
            const int b = (m >= N_NODES) ? 1 : 0;
            const int n = m - b * N_NODES;
            float* fp = &feat[n * 128 + b * 64];
#pragma unroll
            for (int jj = 0; jj < 4; ++jj)
                fp[tx + jj * 16] = acc[ii][jj];
        }
    }

    // el/er: dump acc tile to xs (done with x now), then 512 dot-16 tasks
    __syncthreads();
#pragma unroll
    for (int ii = 0; ii < 4; ++ii)
#pragma unroll
        for (int jj = 0; jj < 4; ++jj)
            xs[(ty + ii * 16) * FC_S + tx + jj * 16] = acc[ii][jj];
    __syncthreads();
#pragma unroll
    for (int pass = 0; pass < 2; ++pass) {
        const int q = pass * 256 + t;       // (row 0..63) x (c 0..7)
        const int row = q >> 3, cc = q & 7;
        const int h = cc & 3, lr = cc >> 2;
        const int m = row0 + row;
        if (m < N_ROWS) {
            const float* av = lr ? ar : al;
            const float* fr = &xs[row * FC_S + h * 16];
            float sum = 0.f;
#pragma unroll
            for (int i = 0; i < 16; ++i)
                sum = fmaf(fr[i], av[h * 16 + i], sum);
            const int b = (m >= N_NODES) ? 1 : 0;
            const int n = m - b * N_NODES;
            (lr ? er : el)[n * 8 + b * 4 + h] = sum;
        }
    }
}

// ---- CSR build --------------------------------------------------------------
__global__ __launch_bounds__(256) void k_hist(const int* __restrict__ dst,
                                              int* __restrict__ deg) {
    const int e = blockIdx.x * 256 + threadIdx.x;   // grid exact 800000/256
    atomicAdd(&deg[dst[e]], 1);
}

__global__ __launch_bounds__(256) void k_alloc(const int* __restrict__ deg,
                                               int* __restrict__ offsets,
                                               int* __restrict__ cursor,
                                               int* __restrict__ gctr) {
    const int i = blockIdx.x * 256 + threadIdx.x;   // grid 196 covers 50176
    const int lane = threadIdx.x & 63;
    const int d = (i < N_NODES) ? deg[i] : 0;
    int incl = d;
#pragma unroll
    for (int off = 1; off < 64; off <<= 1) {
        int v = __shfl_up(incl, off, 64);
        if (lane >= off) incl += v;
    }
    const int wtot = __shfl(incl, 63, 64);
    int wbase = 0;
    if (lane == 63) wbase = atomicAdd(gctr, wtot);
    wbase = __shfl(wbase, 63, 64);
    if (i < N_NODES) {
        const int beg = wbase + incl - d;
        offsets[i] = beg;
        cursor[i] = beg;
    }
}

__global__ __launch_bounds__(256) void k_scatter(const int* __restrict__ src,
                                                 const int* __restrict__ dst,
                                                 const float* __restrict__ w,
                                                 int* __restrict__ cursor,
                                                 int2* __restrict__ srcw) {
    const int e = blockIdx.x * 256 + threadIdx.x;
    const int pos = atomicAdd(&cursor[dst[e]], 1);
    srcw[pos] = make_int2(src[e], __float_as_int(w[e]));
}

// ---- Kernel 2: per-dst gather — softmax numerator + weighted sum ------------
// 32 threads/node, 8 nodes per 256-block; thread owns one float4 (sub 0..31)
__global__ __launch_bounds__(256) void k_gather(const int2* __restrict__ srcw,
                                                const int* __restrict__ offsets,
                                                const int* __restrict__ deg,
                                                const float* __restrict__ el,
                                                const float* __restrict__ er,
                                                const float* __restrict__ feat,
                                                float* __restrict__ denom,
                                                float* __restrict__ rst) {
    const int t = threadIdx.x;
    const int n = blockIdx.x * 8 + (t >> 5);   // grid exact 50000/8
    const int sub = t & 31, c = sub >> 2;
    const int beg = offsets[n], len = deg[n];
    const float ern = er[n * 8 + c];
    const float4* feat4 = (const float4*)feat;
    float4 acc = make_float4(0.f, 0.f, 0.f, 0.f);
    float den = 0.f;
    int k = 0;
    for (; k + 4 <= len; k += 4) {             // 4 independent gather chains
        int2 sw[4];
        float ev[4];
        float4 fv[4];
#pragma unroll
        for (int u = 0; u < 4; ++u) sw[u] = srcw[beg + k + u];
#pragma unroll
        for (int u = 0; u < 4; ++u) ev[u] = el[sw[u].x * 8 + c];
#pragma unroll
        for (int u = 0; u < 4; ++u) fv[u] = feat4[sw[u].x * 32 + sub];
#pragma unroll
        for (int u = 0; u < 4; ++u) {
            const float xx = __expf(__int_as_float(sw[u].y) * lrelu(ev[u] + ern));
            den += xx;
            acc.x = fmaf(xx, fv[u].x, acc.x); acc.y = fmaf(xx, fv[u].y, acc.y);
            acc.z = fmaf(xx, fv[u].z, acc.z); acc.w = fmaf(xx, fv[u].w, acc.w);
        }
    }
    for (; k < len; ++k) {
        const int2 s0 = srcw[beg + k];
        const float e0 = el[s0.x * 8 + c];
        const float4 f0 = feat4[s0.x * 32 + sub];
        const float x0 = __expf(__int_as_float(s0.y) * lrelu(e0 + ern));
        den += x0;
        acc.x = fmaf(x0, f0.x, acc.x); acc.y = fmaf(x0, f0.y, acc.y);
        acc.z = fmaf(x0, f0.z, acc.z); acc.w = fmaf(x0, f0.w, acc.w);
    }
    ((float4*)rst)[n * 32 + sub] = acc;
    if ((sub & 3) == 0) denom[n * 8 + c] = den;
}

// ---- Kernel 3: out = (rst/denom) @ W_out.T + b_out, layout [B,N,H,O] --------
__global__ __launch_bounds__(256) void k_out(const float* __restrict__ rst,
                                             const float* __restrict__ denom,
                                             const float* __restrict__ Wout,
                                             const float* __restrict__ bout,
                                             float* __restrict__ out) {
    __shared__ float rs[1024];
    __shared__ float dn[64];
    const int t = threadIdx.x;
    const int o = t & 63, r = t >> 6;
#pragma unroll
    for (int i = 0; i < 4; ++i)
        rs[i * 256 + t] = rst[blockIdx.x * 1024 + i * 256 + t];
    if (t < 64) dn[t] = denom[blockIdx.x * 64 + t];
    __syncthreads();

    const float4* Wo4 = (const float4*)Wout;
    const float4 wa = Wo4[o * 4 + 0], wb = Wo4[o * 4 + 1];
    const float4 wc = Wo4[o * 4 + 2], wd = Wo4[o * 4 + 3];
    const float bo = bout[o];
#pragma unroll
    for (int i = 0; i < 16; ++i) {
        const int gl = i * 4 + r;              // local g, 0..63
        const float dv = dn[gl];
        const float dinv = (dv > 0.f) ? 1.f / dv : 0.f;
        const float4* r4 = (const float4*)&rs[gl * 16];
        const float4 ra = r4[0], rb = r4[1], rc = r4[2], rd = r4[3];
        float acc = ra.x * wa.x;
        acc = fmaf(ra.y, wa.y, acc); acc = fmaf(ra.z, wa.z, acc); acc = fmaf(ra.w, wa.w, acc);
        acc = fmaf(rb.x, wb.x, acc); acc = fmaf(rb.y, wb.y, acc);
        acc = fmaf(rb.z, wb.z, acc); acc = fmaf(rb.w, wb.w, acc);
        acc = fmaf(rc.x, wc.x, acc); acc = fmaf(rc.y, wc.y, acc);
        acc = fmaf(rc.z, wc.z, acc); acc = fmaf(rc.w, wc.w, acc);
        acc = fmaf(rd.x, wd.x, acc); acc = fmaf(rd.y, wd.y, acc);
        acc = fmaf(rd.z, wd.z, acc); acc = fmaf(rd.w, wd.w, acc);
        acc = fmaf(acc, dinv, bo);
        const int g = blockIdx.x * 64 + gl;    // g = n*8 + b*4 + h
        const int n = g >> 3, b = (g >> 2) & 1, h = g & 3;
        out[b * (N_NODES * 256) + n * 256 + h * 64 + o] = acc;
    }
}

extern "C" void kernel_launch(void* const* d_in, const int* in_sizes, int n_in,
                              void* d_out, int out_size, void* d_ws, size_t ws_size,
                              hipStream_t stream) {
    // setup_inputs order: vt, x, w, src, dst, W_fc, attn_l, attn_r, W_out, b_out
    const float* x    = (const float*)d_in[1];
    const float* w    = (const float*)d_in[2];
    const int*   src  = (const int*)  d_in[3];
    const int*   dst  = (const int*)  d_in[4];
    const float* Wfc  = (const float*)d_in[5];
    const float* al   = (const float*)d_in[6];
    const float* ar   = (const float*)d_in[7];
    const float* Wout = (const float*)d_in[8];
    const float* bout = (const float*)d_in[9];
    float* out = (float*)d_out;

    float* ws    = (float*)d_ws;
    float* feat  = ws;                  // 6,400,000
    float* el    = feat + 6400000;      //   400,000
    float* er    = el + 400000;         //   400,000
    float* denom = er + 400000;         //   400,000
    float* rst   = denom + 400000;      // 6,400,000
    int*   offsets = (int*)(rst + 6400000);   // 50,000
    int*   cursor  = offsets + 50000;         // 50,000
    int*   deg     = cursor + 50000;          // 50,000
    int*   gctr    = deg + 50000;             // 16 (pad)
    int2*  srcw    = (int2*)(gctr + 16);      // 800,000 int2

    hipMemsetAsync(deg, 0, (50000 + 16) * sizeof(int), stream);  // deg + gctr

    k_fc<<<1563, 256, 0, stream>>>(x, Wfc, al, ar, feat, el, er);
    k_hist<<<N_EDGES / 256, 256, 0, stream>>>(dst, deg);
    k_alloc<<<196, 256, 0, stream>>>(deg, offsets, cursor, gctr);
    k_scatter<<<N_EDGES / 256, 256, 0, stream>>>(src, dst, w, cursor, srcw);
    k_gather<<<N_NODES / 8, 256, 0, stream>>>(srcw, offsets, deg, el, er, feat, denom, rst);
    k_out<<<6250, 256, 0, stream>>>(rst, denom, Wout, bout, out);
}